// Round 9
// baseline (573.190 us; speedup 1.0000x reference)
//
#include <hip/hip_runtime.h>

#define DIM 64
#define BIN_SHIFT 7                  // 128 nodes per bin
#define NODES_PER_BIN 128
#define MAX_BINS 1024                // ceil(100000/128)=782 <= 1024
#define BIN_CAP 2048                 // mean 1279, sigma ~36 -> 21-sigma margin
#define CHUNK_EDGES 2048             // edges per bin_scatter block
#define GEMM_ROWS 128                // rows per gemm block
#define ACC_STRIDE 65                // LDS acc row stride: bank=(d+f)%32, de-aliases rows

// ws layout (256-aligned):
// flag | gcur[1024] | dinv[N] | pairs[nbins*BIN_CAP+64] | h[(N+1)*64] bf16
// (h row N = zero dummy row for predicated tail loads)

__device__ __forceinline__ unsigned short f2bf(float f) {
    unsigned u = __float_as_uint(f);
    u += 0x7fffu + ((u >> 16) & 1u);     // round-to-nearest-even
    return (unsigned short)(u >> 16);
}
__device__ __forceinline__ float bf2f(unsigned short u) {
    return __uint_as_float((unsigned)u << 16);
}

// init: detect int64-vs-int32 edge buffer, zero bin cursors, zero dummy h row.
__global__ __launch_bounds__(256) void init_kernel(const int* __restrict__ ei32,
                                                   int* __restrict__ flag,
                                                   int* __restrict__ gcur,
                                                   unsigned short* __restrict__ h, int N) {
    __shared__ int any_nz;
    int tid = threadIdx.x;
    if (tid == 0) any_nz = 0;
    __syncthreads();
    int v = ei32[2 * tid + 1];     // odd int32 words: all-zero iff nonneg int64 data
    if (v != 0) atomicOr(&any_nz, 1);
    for (int i = tid; i < MAX_BINS; i += 256) gcur[i] = 0;
    if (tid < 32) ((unsigned*)(h + (long long)N * DIM))[tid] = 0;   // dummy row
    __syncthreads();
    if (tid == 0) *flag = (any_nz == 0) ? 1 : 0;
}

// Pass 1: scatter packed (src<<7 | dst&127) into fixed-capacity dst-bins.
__global__ __launch_bounds__(256) void bin_scatter_kernel(const void* __restrict__ ei,
                                                          const int* __restrict__ flagp,
                                                          int* __restrict__ gcur,
                                                          int* __restrict__ pairs,
                                                          int E, int nbins) {
    __shared__ int h1[MAX_BINS];
    __shared__ int base[MAX_BINS];
    int tid = threadIdx.x;
    int is64 = *flagp;
    int chunk = blockIdx.x * CHUNK_EDGES;

    int ss[CHUNK_EDGES / 256], dd[CHUNK_EDGES / 256];

    for (int i = tid; i < nbins; i += 256) h1[i] = 0;
    __syncthreads();
#pragma unroll
    for (int k = 0; k < CHUNK_EDGES / 256; ++k) {
        int i = chunk + k * 256 + tid;
        if (i < E) {
            int s, d;
            if (is64) {
                s = (int)((const long long*)ei)[i];
                d = (int)((const long long*)ei)[(long long)i + E];
            } else {
                s = ((const int*)ei)[i];
                d = ((const int*)ei)[i + E];
            }
            ss[k] = s; dd[k] = d;
            atomicAdd(&h1[d >> BIN_SHIFT], 1);
        } else {
            dd[k] = -1;
        }
    }
    __syncthreads();
    for (int i = tid; i < nbins; i += 256) {
        int c = h1[i];
        base[i] = c ? (i * BIN_CAP + atomicAdd(&gcur[i], c)) : 0;
        h1[i] = 0;
    }
    __syncthreads();
#pragma unroll
    for (int k = 0; k < CHUNK_EDGES / 256; ++k) {
        if (dd[k] >= 0) {
            int bin = dd[k] >> BIN_SHIFT;
            int r = atomicAdd(&h1[bin], 1);
            int pos = base[bin] + r;
            if (pos < (bin + 1) * BIN_CAP)          // overflow guard (never expected)
                pairs[pos] = (ss[k] << BIN_SHIFT) | (dd[k] & (NODES_PER_BIN - 1));
        }
    }
}

// Pass 2: per-bin degree histogram -> dinv (bin holds ALL edges of its nodes).
__global__ __launch_bounds__(256) void degree_kernel(const int* __restrict__ pairs,
                                                     const int* __restrict__ gcur,
                                                     float* __restrict__ dinv, int N) {
    __shared__ int sdeg[NODES_PER_BIN];
    int b = blockIdx.x;
    int tid = threadIdx.x;
    int base = b * BIN_CAP;
    int cnt = min(gcur[b], BIN_CAP);
    int node0 = b << BIN_SHIFT;
    int nn = min(NODES_PER_BIN, N - node0);
    if (tid < NODES_PER_BIN) sdeg[tid] = 0;
    __syncthreads();
    for (int i = tid; i < cnt; i += 256)
        atomicAdd(&sdeg[pairs[base + i] & (NODES_PER_BIN - 1)], 1);
    __syncthreads();
    if (tid < nn) dinv[node0 + tid] = rsqrtf((float)(sdeg[tid] + 1));  // +1 self-loop
}

// h[r] = bf16( (x[r] @ W^T) * dinv[r] ).  128x64 tile, thread = 4 rows x 8 cols,
// Xs k-major (bank-conflict-free — round 6's verified fix).
__global__ __launch_bounds__(256, 4) void gemm_kernel(const float* __restrict__ x,
                                                      const float* __restrict__ W,
                                                      const float* __restrict__ dinv,
                                                      unsigned short* __restrict__ h, int N) {
    __shared__ float Wt[64 * 64];               // Wt[k*64+c]
    __shared__ float Xs[64 * GEMM_ROWS];        // Xs[k*128+r]
    int tid = threadIdx.x;
    int row0 = blockIdx.x * GEMM_ROWS;
    int nrows = min(GEMM_ROWS, N - row0);

#pragma unroll
    for (int t = 0; t < 16; ++t) {
        int i = t * 256 + tid;                  // Wt[i], i = k*64+c
        Wt[i] = W[((i & 63) << 6) | (i >> 6)];
    }
    const float* xbase = x + (long long)row0 * DIM;
#pragma unroll
    for (int t = 0; t < 32; ++t) {
        int i = t * 256 + tid;                  // Xs[i], i = k*128+r
        int r = i & (GEMM_ROWS - 1);
        int k = i >> 7;
        Xs[i] = (r < nrows) ? xbase[r * DIM + k] : 0.0f;
    }
    __syncthreads();

    int tc = tid & 7;                           // cols 8*tc .. 8*tc+7
    int tr = tid >> 3;                          // rows 4*tr .. 4*tr+3
    float acc[4][8] = {};
#pragma unroll 4
    for (int k = 0; k < 64; ++k) {
        float4 xv = *(const float4*)&Xs[k * GEMM_ROWS + 4 * tr];
        float4 w0 = *(const float4*)&Wt[k * 64 + 8 * tc];
        float4 w1 = *(const float4*)&Wt[k * 64 + 8 * tc + 4];
        const float* xp = (const float*)&xv;
        const float* wp0 = (const float*)&w0;
        const float* wp1 = (const float*)&w1;
#pragma unroll
        for (int i = 0; i < 4; ++i) {
#pragma unroll
            for (int j = 0; j < 4; ++j) {
                acc[i][j] = fmaf(xp[i], wp0[j], acc[i][j]);
                acc[i][4 + j] = fmaf(xp[i], wp1[j], acc[i][4 + j]);
            }
        }
    }
#pragma unroll
    for (int i = 0; i < 4; ++i) {
        int r = 4 * tr + i;
        if (r < nrows) {
            int g = row0 + r;
            float dv = dinv[g];
            ushort4 o0, o1;
            o0.x = f2bf(acc[i][0] * dv); o0.y = f2bf(acc[i][1] * dv);
            o0.z = f2bf(acc[i][2] * dv); o0.w = f2bf(acc[i][3] * dv);
            o1.x = f2bf(acc[i][4] * dv); o1.y = f2bf(acc[i][5] * dv);
            o1.z = f2bf(acc[i][6] * dv); o1.w = f2bf(acc[i][7] * dv);
            ushort4* hp = (ushort4*)(h + (long long)g * DIM + 8 * tc);
            hp[0] = o0;
            hp[1] = o1;
        }
    }
}

// Pass 3: per-bin aggregate, NO sorted CSR needed. Streams the bin's unsorted
// packed pairs coalesced; 4 bf16 rows per VMEM instr (8 in flight per wave);
// one ds_add_f32 wave-instr per edge into a stride-65 LDS accumulator
// (bank=(d+f)%32 -> rows de-aliased). Epilogue fuses self-loop+dinv+bias.
__global__ __launch_bounds__(256) void bin_aggregate_kernel(
    const unsigned short* __restrict__ h, const int* __restrict__ pairs,
    const int* __restrict__ gcur, const float* __restrict__ dinv,
    const float* __restrict__ bias, float* __restrict__ out, int N) {
    __shared__ float acc[NODES_PER_BIN * ACC_STRIDE];
    int b = blockIdx.x;
    int tid = threadIdx.x;
    int base = b * BIN_CAP;
    int cnt = min(gcur[b], BIN_CAP);
    int node0 = b << BIN_SHIFT;
    int nn = min(NODES_PER_BIN, N - node0);

    for (int i = tid; i < NODES_PER_BIN * ACC_STRIDE; i += 256) acc[i] = 0.0f;
    __syncthreads();

    int wave = tid >> 6, lane = tid & 63;
    int g = lane >> 4;                 // edge slot 0..3
    int fq = lane & 15;                // features 4*fq .. 4*fq+3
    const int* pb = pairs + base;
    int dummy = N << BIN_SHIFT;        // src=N (zero row), dl=0 (adds 0.0 -> harmless)

    for (int j0 = 32 * wave; j0 < cnt; j0 += 128) {
        int pk[8];
#pragma unroll
        for (int u = 0; u < 8; ++u) {
            int e = j0 + 4 * u + g;
            pk[u] = (e < cnt) ? pb[e] : dummy;
        }
        ushort4 r[8];
#pragma unroll
        for (int u = 0; u < 8; ++u)
            r[u] = *(const ushort4*)(h + (long long)(pk[u] >> BIN_SHIFT) * DIM + 4 * fq);
#pragma unroll
        for (int u = 0; u < 8; ++u) {
            float* ar = &acc[(pk[u] & (NODES_PER_BIN - 1)) * ACC_STRIDE + 4 * fq];
            atomicAdd(&ar[0], bf2f(r[u].x));
            atomicAdd(&ar[1], bf2f(r[u].y));
            atomicAdd(&ar[2], bf2f(r[u].z));
            atomicAdd(&ar[3], bf2f(r[u].w));
        }
    }
    __syncthreads();

    for (int ld = wave; ld < nn; ld += 4) {
        int gn = node0 + ld;                       // wave-uniform
        float self = bf2f(h[(long long)gn * DIM + lane]);   // pre-scaled by dinv[gn]
        out[(long long)gn * DIM + lane] =
            (acc[ld * ACC_STRIDE + lane] + self) * dinv[gn] + bias[lane];
    }
}

extern "C" void kernel_launch(void* const* d_in, const int* in_sizes, int n_in,
                              void* d_out, int out_size, void* d_ws, size_t ws_size,
                              hipStream_t stream) {
    const float* x = (const float*)d_in[0];
    const void* ei = d_in[1];
    const float* W = (const float*)d_in[2];
    const float* b = (const float*)d_in[3];
    float* out = (float*)d_out;

    int N = in_sizes[0] / DIM;   // 100000
    int E = in_sizes[1] / 2;     // 1000000
    int nbins = (N + NODES_PER_BIN - 1) >> BIN_SHIFT;   // 782

    char* ws = (char*)d_ws;
    auto align256 = [](size_t v) { return (v + 255) & ~(size_t)255; };
    size_t off = 0;
    int* flag = (int*)(ws + off);              off = align256(off + 4);
    int* gcur = (int*)(ws + off);              off = align256(off + MAX_BINS * 4);
    float* dinv = (float*)(ws + off);          off = align256(off + (size_t)N * 4);
    int* pairs = (int*)(ws + off);             off = align256(off + ((size_t)nbins * BIN_CAP + 64) * 4);
    unsigned short* h = (unsigned short*)(ws + off); off = align256(off + (size_t)(N + 1) * DIM * 2);

    int nchunks = (E + CHUNK_EDGES - 1) / CHUNK_EDGES;       // 489
    int gemmblocks = (N + GEMM_ROWS - 1) / GEMM_ROWS;        // 782

    init_kernel<<<1, 256, 0, stream>>>((const int*)ei, flag, gcur, h, N);
    bin_scatter_kernel<<<nchunks, 256, 0, stream>>>(ei, flag, gcur, pairs, E, nbins);
    degree_kernel<<<nbins, 256, 0, stream>>>(pairs, gcur, dinv, N);
    gemm_kernel<<<gemmblocks, 256, 0, stream>>>(x, W, dinv, h, N);
    bin_aggregate_kernel<<<nbins, 256, 0, stream>>>(h, pairs, gcur, dinv, b, out, N);
}

// Round 10
// 189.384 us; speedup vs baseline: 3.0266x; 3.0266x over previous
//
#include <hip/hip_runtime.h>

#define DIM 64
#define BIN_SHIFT 7                  // 128 nodes per fine bin
#define NODES_PER_BIN 128
#define NBINS_MAX 1024
#define BIN_CAP 2048                 // fine-bin region capacity (mean 1279)
#define SB_SHIFT 14                  // superbin = dst>>14 (8 superbins for N<131072)
#define NSB 8
#define CUR_PAD 16                   // pad each cursor to its own 64B line
#define CHUNK 2048                   // edges per partition block
#define GEMM_ROWS 128

// ws layout (256-aligned):
// flag | sbbase[NSB+1] | sbcur[NSB*16] | gcur[1024*16] | dinv[N] | pofs[N]
// | pairs1[(E+NSB*8192)] int2 | pairs2[nbins*BIN_CAP+64] int | h[(N+1)*64] bf16

__device__ __forceinline__ unsigned short f2bf(float f) {
    unsigned u = __float_as_uint(f);
    u += 0x7fffu + ((u >> 16) & 1u);     // round-to-nearest-even
    return (unsigned short)(u >> 16);
}
__device__ __forceinline__ float bflo(unsigned w) { return __uint_as_float(w << 16); }
__device__ __forceinline__ float bfhi(unsigned w) { return __uint_as_float(w & 0xffff0000u); }

// init: dtype detect, zero fine cursors, superbin bases/cursors, zero dummy h row.
__global__ __launch_bounds__(256) void init_kernel(const int* __restrict__ ei32,
                                                   int* __restrict__ flag,
                                                   int* __restrict__ sbbase,
                                                   int* __restrict__ sbcur,
                                                   int* __restrict__ gcur,
                                                   unsigned short* __restrict__ h,
                                                   int N, int E) {
    __shared__ int any_nz;
    int tid = threadIdx.x;
    if (tid == 0) any_nz = 0;
    __syncthreads();
    int v = ei32[2 * tid + 1];     // odd int32 words: all-zero iff nonneg int64 data
    if (v != 0) atomicOr(&any_nz, 1);
    for (int i = tid; i < NBINS_MAX * CUR_PAD; i += 256) gcur[i] = 0;
    if (tid < 32) ((unsigned*)(h + (long long)N * DIM))[tid] = 0;   // dummy row
    __syncthreads();
    if (tid == 0) {
        *flag = (any_nz == 0) ? 1 : 0;
        long long base = 0;
        for (int s = 0; s < NSB; ++s) {
            int n0 = s << SB_SHIFT;
            int nodes = N - n0;
            nodes = nodes < 0 ? 0 : (nodes > (1 << SB_SHIFT) ? (1 << SB_SHIFT) : nodes);
            int cap = (int)(((long long)nodes * E) / N) + 8192;   // ~20 sigma slack
            sbbase[s] = (int)base;
            sbcur[s * CUR_PAD] = (int)base;
            base += cap;
        }
        sbbase[NSB] = (int)base;
    }
}

// K1: coarse partition into 8 superbins. Runs of ~256 int2 -> dense writes.
__global__ __launch_bounds__(256) void coarse_kernel(const void* __restrict__ ei,
                                                     const int* __restrict__ flagp,
                                                     const int* __restrict__ sbbase,
                                                     int* __restrict__ sbcur,
                                                     int2* __restrict__ pairs1, int E) {
    __shared__ int h1[NSB];
    __shared__ int base[NSB];
    int tid = threadIdx.x;
    int is64 = *flagp;
    int chunk = blockIdx.x * CHUNK;
    int ss[CHUNK / 256], dd[CHUNK / 256];

    if (tid < NSB) h1[tid] = 0;
    __syncthreads();
#pragma unroll
    for (int k = 0; k < CHUNK / 256; ++k) {
        int i = chunk + k * 256 + tid;
        if (i < E) {
            int s, d;
            if (is64) {
                s = (int)((const long long*)ei)[i];
                d = (int)((const long long*)ei)[(long long)i + E];
            } else {
                s = ((const int*)ei)[i];
                d = ((const int*)ei)[i + E];
            }
            ss[k] = s; dd[k] = d;
            atomicAdd(&h1[(d >> SB_SHIFT) & (NSB - 1)], 1);
        } else {
            dd[k] = -1;
        }
    }
    __syncthreads();
    if (tid < NSB) {
        int c = h1[tid];
        base[tid] = c ? atomicAdd(&sbcur[tid * CUR_PAD], c) : 0;
        h1[tid] = 0;
    }
    __syncthreads();
#pragma unroll
    for (int k = 0; k < CHUNK / 256; ++k) {
        if (dd[k] >= 0) {
            int sb = (dd[k] >> SB_SHIFT) & (NSB - 1);
            int r = atomicAdd(&h1[sb], 1);
            int pos = base[sb] + r;
            if (pos < sbbase[sb + 1])               // overflow guard (never expected)
                pairs1[pos] = make_int2(ss[k], dd[k]);
        }
    }
}

// K2: fine partition of one superbin chunk into <=128 fine bins (BIN_CAP regions).
// Runs of ~21 packed ints -> ~1.3x write amplification (vs ~16x in one-shot scatter).
__global__ __launch_bounds__(256) void fine_kernel(const int2* __restrict__ pairs1,
                                                   const int* __restrict__ sbbase,
                                                   const int* __restrict__ sbcur,
                                                   int* __restrict__ gcur,
                                                   int* __restrict__ pairs2) {
    int b = blockIdx.x;
    int sb = b >> 7;                 // 128 chunk-slots per superbin
    int c = b & 127;
    int start = sbbase[sb];
    int used = sbcur[sb * CUR_PAD] - start;
    int seg = c * CHUNK;
    if (seg >= used) return;
    int cnt = min(CHUNK, used - seg);
    const int2* pb = pairs1 + start + seg;

    __shared__ int h1[NODES_PER_BIN];
    __shared__ int base[NODES_PER_BIN];
    int tid = threadIdx.x;
    int px[CHUNK / 256], py[CHUNK / 256];

    if (tid < NODES_PER_BIN) h1[tid] = 0;
    __syncthreads();
#pragma unroll
    for (int k = 0; k < CHUNK / 256; ++k) {
        int i = k * 256 + tid;
        if (i < cnt) {
            int2 e = pb[i];
            px[k] = e.x; py[k] = e.y;
            atomicAdd(&h1[(e.y >> BIN_SHIFT) & 127], 1);
        } else {
            py[k] = -1;
        }
    }
    __syncthreads();
    if (tid < NODES_PER_BIN) {
        int cc = h1[tid];
        int f = (sb << 7) | tid;
        base[tid] = cc ? (f * BIN_CAP + atomicAdd(&gcur[f * CUR_PAD], cc)) : 0;
        h1[tid] = 0;
    }
    __syncthreads();
#pragma unroll
    for (int k = 0; k < CHUNK / 256; ++k) {
        if (py[k] >= 0) {
            int lb = (py[k] >> BIN_SHIFT) & 127;
            int r = atomicAdd(&h1[lb], 1);
            int pos = base[lb] + r;
            int f = py[k] >> BIN_SHIFT;
            if (pos < (f + 1) * BIN_CAP)            // overflow guard (never expected)
                pairs2[pos] = (px[k] << BIN_SHIFT) | (py[k] & (NODES_PER_BIN - 1));
        }
    }
}

// Pass: per-bin CSR build (round-8 verified): edges once into regs, LDS counting
// sort, in-place writeback of src ids; emits packed pofs (ofs<<11|deg) + dinv.
__global__ __launch_bounds__(256) void bin_csr_kernel(int* __restrict__ pairs,
                                                      const int* __restrict__ gcur,
                                                      unsigned* __restrict__ pofs,
                                                      float* __restrict__ dinv, int N) {
    __shared__ int csr[BIN_CAP];
    __shared__ int sdeg[NODES_PER_BIN];
    __shared__ int sofs[NODES_PER_BIN];
    __shared__ int scur[NODES_PER_BIN];
    int b = blockIdx.x;
    int tid = threadIdx.x;
    int base = b * BIN_CAP;
    int cnt = min(gcur[b * CUR_PAD], BIN_CAP);
    int node0 = b << BIN_SHIFT;
    int nn = min(NODES_PER_BIN, N - node0);

    int p[BIN_CAP / 256];
    if (tid < NODES_PER_BIN) sdeg[tid] = 0;
    __syncthreads();
#pragma unroll
    for (int t = 0; t < BIN_CAP / 256; ++t) {
        int i = t * 256 + tid;
        if (i < cnt) {
            p[t] = pairs[base + i];
            atomicAdd(&sdeg[p[t] & (NODES_PER_BIN - 1)], 1);
        } else {
            p[t] = -1;
        }
    }
    __syncthreads();
    if (tid < NODES_PER_BIN) sofs[tid] = sdeg[tid];
    __syncthreads();
    for (int off = 1; off < NODES_PER_BIN; off <<= 1) {
        int v = (tid >= off && tid < NODES_PER_BIN) ? sofs[tid - off] : 0;
        __syncthreads();
        if (tid < NODES_PER_BIN) sofs[tid] += v;
        __syncthreads();
    }
    if (tid < NODES_PER_BIN) {
        int e = sofs[tid] - sdeg[tid];
        sofs[tid] = e;
        scur[tid] = e;
        if (tid < nn) {
            int g = node0 + tid;
            int dgc = min(sdeg[tid], 2047);
            pofs[g] = ((unsigned)(base + e) << 11) | (unsigned)dgc;
            dinv[g] = rsqrtf((float)(sdeg[tid] + 1));   // +1 self-loop
        }
    }
    __syncthreads();
#pragma unroll
    for (int t = 0; t < BIN_CAP / 256; ++t) {
        if (p[t] >= 0) {
            int r = atomicAdd(&scur[p[t] & (NODES_PER_BIN - 1)], 1);
            csr[r] = p[t] >> BIN_SHIFT;                  // src id
        }
    }
    __syncthreads();
    for (int i = tid; i < cnt; i += 256) pairs[base + i] = csr[i];
}

// h[r] = bf16( (x[r] @ W^T) * dinv[r] ).  128x64 tile, thread = 4 rows x 8 cols,
// Xs k-major (bank-conflict-free — round-6 verified).
__global__ __launch_bounds__(256, 4) void gemm_kernel(const float* __restrict__ x,
                                                      const float* __restrict__ W,
                                                      const float* __restrict__ dinv,
                                                      unsigned short* __restrict__ h, int N) {
    __shared__ float Wt[64 * 64];               // Wt[k*64+c]
    __shared__ float Xs[64 * GEMM_ROWS];        // Xs[k*128+r]
    int tid = threadIdx.x;
    int row0 = blockIdx.x * GEMM_ROWS;
    int nrows = min(GEMM_ROWS, N - row0);

#pragma unroll
    for (int t = 0; t < 16; ++t) {
        int i = t * 256 + tid;
        Wt[i] = W[((i & 63) << 6) | (i >> 6)];
    }
    const float* xbase = x + (long long)row0 * DIM;
#pragma unroll
    for (int t = 0; t < 32; ++t) {
        int i = t * 256 + tid;
        int r = i & (GEMM_ROWS - 1);
        int k = i >> 7;
        Xs[i] = (r < nrows) ? xbase[r * DIM + k] : 0.0f;
    }
    __syncthreads();

    int tc = tid & 7;
    int tr = tid >> 3;
    float acc[4][8] = {};
#pragma unroll 4
    for (int k = 0; k < 64; ++k) {
        float4 xv = *(const float4*)&Xs[k * GEMM_ROWS + 4 * tr];
        float4 w0 = *(const float4*)&Wt[k * 64 + 8 * tc];
        float4 w1 = *(const float4*)&Wt[k * 64 + 8 * tc + 4];
        const float* xp = (const float*)&xv;
        const float* wp0 = (const float*)&w0;
        const float* wp1 = (const float*)&w1;
#pragma unroll
        for (int i = 0; i < 4; ++i) {
#pragma unroll
            for (int j = 0; j < 4; ++j) {
                acc[i][j] = fmaf(xp[i], wp0[j], acc[i][j]);
                acc[i][4 + j] = fmaf(xp[i], wp1[j], acc[i][4 + j]);
            }
        }
    }
#pragma unroll
    for (int i = 0; i < 4; ++i) {
        int r = 4 * tr + i;
        if (r < nrows) {
            int g = row0 + r;
            float dv = dinv[g];
            ushort4 o0, o1;
            o0.x = f2bf(acc[i][0] * dv); o0.y = f2bf(acc[i][1] * dv);
            o0.z = f2bf(acc[i][2] * dv); o0.w = f2bf(acc[i][3] * dv);
            o1.x = f2bf(acc[i][4] * dv); o1.y = f2bf(acc[i][5] * dv);
            o1.z = f2bf(acc[i][6] * dv); o1.w = f2bf(acc[i][7] * dv);
            ushort4* hp = (ushort4*)(h + (long long)g * DIM + 8 * tc);
            hp[0] = o0;
            hp[1] = o1;
        }
    }
}

// Gather: wave-per-node, 8 edges per VMEM instruction.
// lane = (g = lane>>3: edge slot, fo = lane&7: feature octet). Each lane loads
// uint4 (16B = 8 bf16) of row srcs[st+j+g]; tail slots predicated to zero row N.
// One index-load + one row-load instruction per 8 edges; 3 shfl_xor reduce.
__global__ __launch_bounds__(256) void gather_kernel(const unsigned short* __restrict__ h,
                                                     const unsigned* __restrict__ pofs,
                                                     const int* __restrict__ srcs,
                                                     const float* __restrict__ dinv,
                                                     const float* __restrict__ bias,
                                                     float* __restrict__ out, int N) {
    int node = (blockIdx.x * blockDim.x + threadIdx.x) >> 6;
    if (node >= N) return;
    int lane = threadIdx.x & 63;
    int g = lane >> 3;                 // edge slot 0..7
    int fo = lane & 7;                 // features 8*fo .. 8*fo+7
    unsigned pk = pofs[node];
    int st = (int)(pk >> 11);
    int dg = (int)(pk & 2047u);
    const uint4* hv = (const uint4*)h;     // row r = 8 uint4s

    float a0 = 0, a1 = 0, a2 = 0, a3 = 0, a4 = 0, a5 = 0, a6 = 0, a7 = 0;
    if (g == 0) {                      // self-loop (h pre-scaled by dinv[node])
        uint4 sv = hv[(long long)node * 8 + fo];
        a0 = bflo(sv.x); a1 = bfhi(sv.x); a2 = bflo(sv.y); a3 = bfhi(sv.y);
        a4 = bflo(sv.z); a5 = bfhi(sv.z); a6 = bflo(sv.w); a7 = bfhi(sv.w);
    }

    for (int j = 0; j < dg; j += 8) {
        int e = j + g;
        int s = srcs[st + e];          // in-bounds of padded pairs2 even past dg
        s = (e < dg) ? s : N;          // predicate tail to zero dummy row
        uint4 u = hv[(long long)s * 8 + fo];
        a0 += bflo(u.x); a1 += bfhi(u.x); a2 += bflo(u.y); a3 += bfhi(u.y);
        a4 += bflo(u.z); a5 += bfhi(u.z); a6 += bflo(u.w); a7 += bfhi(u.w);
    }

    a0 += __shfl_xor(a0, 8); a0 += __shfl_xor(a0, 16); a0 += __shfl_xor(a0, 32);
    a1 += __shfl_xor(a1, 8); a1 += __shfl_xor(a1, 16); a1 += __shfl_xor(a1, 32);
    a2 += __shfl_xor(a2, 8); a2 += __shfl_xor(a2, 16); a2 += __shfl_xor(a2, 32);
    a3 += __shfl_xor(a3, 8); a3 += __shfl_xor(a3, 16); a3 += __shfl_xor(a3, 32);
    a4 += __shfl_xor(a4, 8); a4 += __shfl_xor(a4, 16); a4 += __shfl_xor(a4, 32);
    a5 += __shfl_xor(a5, 8); a5 += __shfl_xor(a5, 16); a5 += __shfl_xor(a5, 32);
    a6 += __shfl_xor(a6, 8); a6 += __shfl_xor(a6, 16); a6 += __shfl_xor(a6, 32);
    a7 += __shfl_xor(a7, 8); a7 += __shfl_xor(a7, 16); a7 += __shfl_xor(a7, 32);

    if (lane < 8) {                    // lane == fo, g == 0
        float dn = dinv[node];
        float4 b0 = *(const float4*)&bias[8 * fo];
        float4 b1 = *(const float4*)&bias[8 * fo + 4];
        float* op = out + (long long)node * DIM + 8 * fo;
        *(float4*)op = make_float4(a0 * dn + b0.x, a1 * dn + b0.y,
                                   a2 * dn + b0.z, a3 * dn + b0.w);
        *(float4*)(op + 4) = make_float4(a4 * dn + b1.x, a5 * dn + b1.y,
                                         a6 * dn + b1.z, a7 * dn + b1.w);
    }
}

extern "C" void kernel_launch(void* const* d_in, const int* in_sizes, int n_in,
                              void* d_out, int out_size, void* d_ws, size_t ws_size,
                              hipStream_t stream) {
    const float* x = (const float*)d_in[0];
    const void* ei = d_in[1];
    const float* W = (const float*)d_in[2];
    const float* b = (const float*)d_in[3];
    float* out = (float*)d_out;

    int N = in_sizes[0] / DIM;   // 100000
    int E = in_sizes[1] / 2;     // 1000000
    int nbins = (N + NODES_PER_BIN - 1) >> BIN_SHIFT;   // 782

    char* ws = (char*)d_ws;
    auto align256 = [](size_t v) { return (v + 255) & ~(size_t)255; };
    size_t off = 0;
    int* flag = (int*)(ws + off);              off = align256(off + 4);
    int* sbbase = (int*)(ws + off);            off = align256(off + (NSB + 1) * 4);
    int* sbcur = (int*)(ws + off);             off = align256(off + NSB * CUR_PAD * 4);
    int* gcur = (int*)(ws + off);              off = align256(off + (size_t)NBINS_MAX * CUR_PAD * 4);
    float* dinv = (float*)(ws + off);          off = align256(off + (size_t)N * 4);
    unsigned* pofs = (unsigned*)(ws + off);    off = align256(off + (size_t)N * 4);
    int2* pairs1 = (int2*)(ws + off);          off = align256(off + ((size_t)E + NSB * 8192) * 8);
    int* pairs2 = (int*)(ws + off);            off = align256(off + ((size_t)nbins * BIN_CAP + 64) * 4);
    unsigned short* h = (unsigned short*)(ws + off); off = align256(off + (size_t)(N + 1) * DIM * 2);

    int k1blocks = (E + CHUNK - 1) / CHUNK;                  // 489
    int k2blocks = NSB * 128;                                // 1024 (early-exit empties)
    int gemmblocks = (N + GEMM_ROWS - 1) / GEMM_ROWS;        // 782
    int gblocks = (N + 3) / 4;                               // wave-per-node

    init_kernel<<<1, 256, 0, stream>>>((const int*)ei, flag, sbbase, sbcur, gcur, h, N, E);
    coarse_kernel<<<k1blocks, 256, 0, stream>>>(ei, flag, sbbase, sbcur, pairs1, E);
    fine_kernel<<<k2blocks, 256, 0, stream>>>(pairs1, sbbase, sbcur, gcur, pairs2);
    bin_csr_kernel<<<nbins, 256, 0, stream>>>(pairs2, gcur, pofs, dinv, N);
    gemm_kernel<<<gemmblocks, 256, 0, stream>>>(x, W, dinv, h, N);
    gather_kernel<<<gblocks, 256, 0, stream>>>(h, pofs, pairs2, dinv, b, out, N);
}

// Round 11
// 166.833 us; speedup vs baseline: 3.4357x; 1.1352x over previous
//
#include <hip/hip_runtime.h>

#define DIM 64
#define BIN_SHIFT 7                  // 128 nodes per bin
#define NODES_PER_BIN 128
#define MAX_BINS 1024                // ceil(100000/128)=782 <= 1024
#define BIN_CAP 2048                 // mean 1279, sigma ~36 -> 21-sigma margin
#define CHUNK_EDGES 2048             // edges per bin_scatter block
#define GEMM_ROWS 128                // rows per gemm block
#define ACC_STRIDE 65                // LDS acc row stride: bank=(d+f)%32, rows de-aliased
#define FXSCALE 65536.0f             // fixed-point scale 2^16
#define FXINV (1.0f / 65536.0f)

// ws layout (256-aligned):
// flag | gcur[1024] | dinv[N] | pairs[nbins*BIN_CAP+64] | h[(N+1)*64] bf16
// (h row N = zero dummy row for predicated tail loads)

__device__ __forceinline__ unsigned short f2bf(float f) {
    unsigned u = __float_as_uint(f);
    u += 0x7fffu + ((u >> 16) & 1u);     // round-to-nearest-even
    return (unsigned short)(u >> 16);
}
__device__ __forceinline__ float bf2f(unsigned short u) {
    return __uint_as_float((unsigned)u << 16);
}
__device__ __forceinline__ int fx(float v) {        // float -> fixed-point int
    return (int)rintf(v * FXSCALE);
}

// init: detect int64-vs-int32 edge buffer, zero bin cursors, zero dummy h row.
__global__ __launch_bounds__(256) void init_kernel(const int* __restrict__ ei32,
                                                   int* __restrict__ flag,
                                                   int* __restrict__ gcur,
                                                   unsigned short* __restrict__ h, int N) {
    __shared__ int any_nz;
    int tid = threadIdx.x;
    if (tid == 0) any_nz = 0;
    __syncthreads();
    int v = ei32[2 * tid + 1];     // odd int32 words: all-zero iff nonneg int64 data
    if (v != 0) atomicOr(&any_nz, 1);
    for (int i = tid; i < MAX_BINS; i += 256) gcur[i] = 0;
    if (tid < 32) ((unsigned*)(h + (long long)N * DIM))[tid] = 0;   // dummy row
    __syncthreads();
    if (tid == 0) *flag = (any_nz == 0) ? 1 : 0;
}

// Pass 1 (round-8 verified): scatter packed (src<<7 | dst&127) into dst-bins.
// One reservation atomic per (block,bin); contiguous write runs.
__global__ __launch_bounds__(256) void bin_scatter_kernel(const void* __restrict__ ei,
                                                          const int* __restrict__ flagp,
                                                          int* __restrict__ gcur,
                                                          int* __restrict__ pairs,
                                                          int E, int nbins) {
    __shared__ int h1[MAX_BINS];
    __shared__ int base[MAX_BINS];
    int tid = threadIdx.x;
    int is64 = *flagp;
    int chunk = blockIdx.x * CHUNK_EDGES;

    int ss[CHUNK_EDGES / 256], dd[CHUNK_EDGES / 256];

    for (int i = tid; i < nbins; i += 256) h1[i] = 0;
    __syncthreads();
#pragma unroll
    for (int k = 0; k < CHUNK_EDGES / 256; ++k) {
        int i = chunk + k * 256 + tid;
        if (i < E) {
            int s, d;
            if (is64) {
                s = (int)((const long long*)ei)[i];
                d = (int)((const long long*)ei)[(long long)i + E];
            } else {
                s = ((const int*)ei)[i];
                d = ((const int*)ei)[i + E];
            }
            ss[k] = s; dd[k] = d;
            atomicAdd(&h1[d >> BIN_SHIFT], 1);
        } else {
            dd[k] = -1;
        }
    }
    __syncthreads();
    for (int i = tid; i < nbins; i += 256) {
        int c = h1[i];
        base[i] = c ? (i * BIN_CAP + atomicAdd(&gcur[i], c)) : 0;
        h1[i] = 0;
    }
    __syncthreads();
#pragma unroll
    for (int k = 0; k < CHUNK_EDGES / 256; ++k) {
        if (dd[k] >= 0) {
            int bin = dd[k] >> BIN_SHIFT;
            int r = atomicAdd(&h1[bin], 1);
            int pos = base[bin] + r;
            if (pos < (bin + 1) * BIN_CAP)          // overflow guard (never expected)
                pairs[pos] = (ss[k] << BIN_SHIFT) | (dd[k] & (NODES_PER_BIN - 1));
        }
    }
}

// Pass 2: per-bin degree histogram -> dinv (bin holds ALL edges of its nodes).
// Native ds_add_u32 int atomics.
__global__ __launch_bounds__(256) void degree_kernel(const int* __restrict__ pairs,
                                                     const int* __restrict__ gcur,
                                                     float* __restrict__ dinv, int N) {
    __shared__ int sdeg[NODES_PER_BIN];
    int b = blockIdx.x;
    int tid = threadIdx.x;
    int base = b * BIN_CAP;
    int cnt = min(gcur[b], BIN_CAP);
    int node0 = b << BIN_SHIFT;
    int nn = min(NODES_PER_BIN, N - node0);
    if (tid < NODES_PER_BIN) sdeg[tid] = 0;
    __syncthreads();
    for (int i = tid; i < cnt; i += 256)
        atomicAdd(&sdeg[pairs[base + i] & (NODES_PER_BIN - 1)], 1);
    __syncthreads();
    if (tid < nn) dinv[node0 + tid] = rsqrtf((float)(sdeg[tid] + 1));  // +1 self-loop
}

// h[r] = bf16( (x[r] @ W^T) * dinv[r] ).  128x64 tile, thread = 4 rows x 8 cols,
// Xs k-major (bank-conflict-free — round-6 verified).
__global__ __launch_bounds__(256, 4) void gemm_kernel(const float* __restrict__ x,
                                                      const float* __restrict__ W,
                                                      const float* __restrict__ dinv,
                                                      unsigned short* __restrict__ h, int N) {
    __shared__ float Wt[64 * 64];               // Wt[k*64+c]
    __shared__ float Xs[64 * GEMM_ROWS];        // Xs[k*128+r]
    int tid = threadIdx.x;
    int row0 = blockIdx.x * GEMM_ROWS;
    int nrows = min(GEMM_ROWS, N - row0);

#pragma unroll
    for (int t = 0; t < 16; ++t) {
        int i = t * 256 + tid;
        Wt[i] = W[((i & 63) << 6) | (i >> 6)];
    }
    const float* xbase = x + (long long)row0 * DIM;
#pragma unroll
    for (int t = 0; t < 32; ++t) {
        int i = t * 256 + tid;
        int r = i & (GEMM_ROWS - 1);
        int k = i >> 7;
        Xs[i] = (r < nrows) ? xbase[r * DIM + k] : 0.0f;
    }
    __syncthreads();

    int tc = tid & 7;
    int tr = tid >> 3;
    float acc[4][8] = {};
#pragma unroll 4
    for (int k = 0; k < 64; ++k) {
        float4 xv = *(const float4*)&Xs[k * GEMM_ROWS + 4 * tr];
        float4 w0 = *(const float4*)&Wt[k * 64 + 8 * tc];
        float4 w1 = *(const float4*)&Wt[k * 64 + 8 * tc + 4];
        const float* xp = (const float*)&xv;
        const float* wp0 = (const float*)&w0;
        const float* wp1 = (const float*)&w1;
#pragma unroll
        for (int i = 0; i < 4; ++i) {
#pragma unroll
            for (int j = 0; j < 4; ++j) {
                acc[i][j] = fmaf(xp[i], wp0[j], acc[i][j]);
                acc[i][4 + j] = fmaf(xp[i], wp1[j], acc[i][4 + j]);
            }
        }
    }
#pragma unroll
    for (int i = 0; i < 4; ++i) {
        int r = 4 * tr + i;
        if (r < nrows) {
            int g = row0 + r;
            float dv = dinv[g];
            ushort4 o0, o1;
            o0.x = f2bf(acc[i][0] * dv); o0.y = f2bf(acc[i][1] * dv);
            o0.z = f2bf(acc[i][2] * dv); o0.w = f2bf(acc[i][3] * dv);
            o1.x = f2bf(acc[i][4] * dv); o1.y = f2bf(acc[i][5] * dv);
            o1.z = f2bf(acc[i][6] * dv); o1.w = f2bf(acc[i][7] * dv);
            ushort4* hp = (ushort4*)(h + (long long)g * DIM + 8 * tc);
            hp[0] = o0;
            hp[1] = o1;
        }
    }
}

// Pass 3: per-bin aggregate, CSR-free, FIXED-POINT int LDS accumulation
// (native ds_add_u32 — round 9's CAS-loop float atomics were the poison).
// Streams unsorted packed pairs coalesced; 8 independent bf16 row loads in
// flight per wave; 1 int LDS atomic wave-instr per edge; epilogue fuses
// self-loop + dinv[dst] + bias.
__global__ __launch_bounds__(256) void bin_aggregate_kernel(
    const unsigned short* __restrict__ h, const int* __restrict__ pairs,
    const int* __restrict__ gcur, const float* __restrict__ dinv,
    const float* __restrict__ bias, float* __restrict__ out, int N) {
    __shared__ int acc[NODES_PER_BIN * ACC_STRIDE];
    int b = blockIdx.x;
    int tid = threadIdx.x;
    int base = b * BIN_CAP;
    int cnt = min(gcur[b], BIN_CAP);
    int node0 = b << BIN_SHIFT;
    int nn = min(NODES_PER_BIN, N - node0);

    for (int i = tid; i < NODES_PER_BIN * ACC_STRIDE; i += 256) acc[i] = 0;
    __syncthreads();

    int wave = tid >> 6, lane = tid & 63;
    int g = lane >> 4;                 // edge slot 0..3
    int fq = lane & 15;                // features 4*fq .. 4*fq+3
    const int* pb = pairs + base;
    int dummy = N << BIN_SHIFT;        // src=N (zero row), local dst=0 (adds 0)

    for (int j0 = 32 * wave; j0 < cnt; j0 += 128) {
        int pk[8];
#pragma unroll
        for (int u = 0; u < 8; ++u) {
            int e = j0 + 4 * u + g;
            pk[u] = (e < cnt) ? pb[e] : dummy;
        }
        ushort4 r[8];
#pragma unroll
        for (int u = 0; u < 8; ++u)
            r[u] = *(const ushort4*)(h + (long long)(pk[u] >> BIN_SHIFT) * DIM + 4 * fq);
#pragma unroll
        for (int u = 0; u < 8; ++u) {
            int* ar = &acc[(pk[u] & (NODES_PER_BIN - 1)) * ACC_STRIDE + 4 * fq];
            atomicAdd(&ar[0], fx(bf2f(r[u].x)));
            atomicAdd(&ar[1], fx(bf2f(r[u].y)));
            atomicAdd(&ar[2], fx(bf2f(r[u].z)));
            atomicAdd(&ar[3], fx(bf2f(r[u].w)));
        }
    }
    __syncthreads();

    for (int ld = wave; ld < nn; ld += 4) {
        int gn = node0 + ld;                                // wave-uniform
        float self = bf2f(h[(long long)gn * DIM + lane]);   // pre-scaled by dinv[gn]
        float sum = (float)acc[ld * ACC_STRIDE + lane] * FXINV + self;
        out[(long long)gn * DIM + lane] = sum * dinv[gn] + bias[lane];
    }
}

extern "C" void kernel_launch(void* const* d_in, const int* in_sizes, int n_in,
                              void* d_out, int out_size, void* d_ws, size_t ws_size,
                              hipStream_t stream) {
    const float* x = (const float*)d_in[0];
    const void* ei = d_in[1];
    const float* W = (const float*)d_in[2];
    const float* b = (const float*)d_in[3];
    float* out = (float*)d_out;

    int N = in_sizes[0] / DIM;   // 100000
    int E = in_sizes[1] / 2;     // 1000000
    int nbins = (N + NODES_PER_BIN - 1) >> BIN_SHIFT;   // 782

    char* ws = (char*)d_ws;
    auto align256 = [](size_t v) { return (v + 255) & ~(size_t)255; };
    size_t off = 0;
    int* flag = (int*)(ws + off);              off = align256(off + 4);
    int* gcur = (int*)(ws + off);              off = align256(off + MAX_BINS * 4);
    float* dinv = (float*)(ws + off);          off = align256(off + (size_t)N * 4);
    int* pairs = (int*)(ws + off);             off = align256(off + ((size_t)nbins * BIN_CAP + 64) * 4);
    unsigned short* h = (unsigned short*)(ws + off); off = align256(off + (size_t)(N + 1) * DIM * 2);

    int nchunks = (E + CHUNK_EDGES - 1) / CHUNK_EDGES;       // 489
    int gemmblocks = (N + GEMM_ROWS - 1) / GEMM_ROWS;        // 782

    init_kernel<<<1, 256, 0, stream>>>((const int*)ei, flag, gcur, h, N);
    bin_scatter_kernel<<<nchunks, 256, 0, stream>>>(ei, flag, gcur, pairs, E, nbins);
    degree_kernel<<<nbins, 256, 0, stream>>>(pairs, gcur, dinv, N);
    gemm_kernel<<<gemmblocks, 256, 0, stream>>>(x, W, dinv, h, N);
    bin_aggregate_kernel<<<nbins, 256, 0, stream>>>(h, pairs, gcur, dinv, b, out, N);
}